// Round 4
// baseline (9693.576 us; speedup 1.0000x reference)
//
#include <hip/hip_runtime.h>
#include <hip/hip_bf16.h>
#include <math.h>

#define LLc  4
#define BBc  2
#define SSc  2048
#define FFc  256
#define HHc  8
#define DKc  32
#define MMc  10
#define HDKc 256
#define F4c  1024
#define NRc  4096          /* B*S */
#define NEGF (-4294967295.0f)
#define ISQD 0.17677669529663687f  /* 1/sqrt(32) */

typedef unsigned short u16;
typedef unsigned int   u32;

__device__ __forceinline__ int rel_index(int pi, int pj) {
    int dd = pi - pj; if (dd < 0) dd = -dd;
    if (dd <= MMc) return dd;
    int t = (int)(10.0f + log2f((float)(dd - MMc)));
    return t > 2 * MMc ? 2 * MMc : t;
}

__global__ __launch_bounds__(256)
void fill_f32(float* __restrict__ p, float v) {
    p[(size_t)blockIdx.x * 256 + threadIdx.x] = v;
}

// ---- naive QKV projection: one thread per (row r, col c) of [4096 x 256];
// scatter into heads layout [B*H, S, DK].
__global__ __launch_bounds__(256)
void proj_qkv(const float* __restrict__ X, const float* __restrict__ W,
              const float* __restrict__ bias, float* __restrict__ Out)
{
    const int id = blockIdx.x * 256 + threadIdx.x;   // 4096*256 total
    const int r = id >> 8, c = id & 255;
    const float* xr = X + (size_t)r * FFc;
    const float* wc = W + c;
    float acc = bias[c];
    for (int k = 0; k < FFc; ++k) acc += xr[k] * wc[(size_t)k * HDKc];
    const int b = r >> 11, s = r & (SSc - 1), h = c >> 5, d = c & 31;
    Out[((size_t)(b * HHc + h) * SSc + s) * DKc + d] = acc;
}

// ---- naive GEMM: C[rows x Nc] = A[rows x Kd] @ W[Kd x Nc] + bias. MODE2 = exact GELU.
template<int MODE, int Nc, int Kd>
__global__ __launch_bounds__(256)
void mm_naive(const float* __restrict__ A, const float* __restrict__ W,
              const float* __restrict__ bias, float* __restrict__ C)
{
    const int id = blockIdx.x * 256 + threadIdx.x;
    const int r = id / Nc, c = id - r * Nc;
    const float* ar = A + (size_t)r * Kd;
    const float* wc = W + c;
    float acc = bias[c];
    for (int k = 0; k < Kd; ++k) acc += ar[k] * wc[(size_t)k * Nc];
    if (MODE == 2) acc = 0.5f * acc * (1.0f + erff(acc * 0.70710678118654752f));
    C[(size_t)r * Nc + c] = acc;
}

// ---- LayerNorm over F=256, one wave per row ----
template<bool FINAL>
__global__ __launch_bounds__(256)
void ln_kernel(const float* __restrict__ Xi, const float* __restrict__ g,
               const float* __restrict__ bia, float* __restrict__ Y,
               float* __restrict__ Yout)
{
    const int row = blockIdx.x * 4 + (threadIdx.x >> 6);
    const int lane = threadIdx.x & 63;
    const float4 v = *(const float4*)&Xi[(size_t)row * FFc + lane * 4];
    float s = v.x + v.y + v.z + v.w;
    float s2 = v.x * v.x + v.y * v.y + v.z * v.z + v.w * v.w;
#pragma unroll
    for (int m = 1; m < 64; m <<= 1) { s += __shfl_xor(s, m); s2 += __shfl_xor(s2, m); }
    const float mu = s * (1.0f / FFc);
    float var = s2 * (1.0f / FFc) - mu * mu;
    var = fmaxf(var, 0.0f);
    const float inv = 1.0f / sqrtf(var + 1e-5f);
    const float4 gv = *(const float4*)&g[lane * 4];
    const float4 bv = *(const float4*)&bia[lane * 4];
    float4 o;
    o.x = (v.x - mu) * inv * gv.x + bv.x;
    o.y = (v.y - mu) * inv * gv.y + bv.y;
    o.z = (v.z - mu) * inv * gv.z + bv.z;
    o.w = (v.w - mu) * inv * gv.w + bv.w;
    *(float4*)&Y[(size_t)row * FFc + lane * 4] = o;
    if (FINAL) {
        *(float4*)&Yout[(size_t)row * FFc + lane * 4] = o;
    }
}

// ---- naive flash attention: block = 4 waves = 4 query rows; one kernel, two passes.
// Pass 1: online (m,l) + PV with lane<32 owning output dim. Pass 2: p=exp(s-m)/l -> att RMW (f32).
__global__ __launch_bounds__(256)
void attn_naive(const float* __restrict__ Qg, const float* __restrict__ Kg,
                const float* __restrict__ Vg,
                const int* __restrict__ posg, const int* __restrict__ maskg,
                const float* __restrict__ rk_t, const float* __restrict__ rb_t,
                float* __restrict__ att, float* __restrict__ Ob,
                int addmode, float scalef)
{
    __shared__ float Ks[64][33];
    __shared__ float Vs[64][33];
    __shared__ float Pr[4][64];
    __shared__ float rks[2 * MMc + 1], rbs[2 * MMc + 1];

    const int tid = threadIdx.x;
    const int w = tid >> 6, lane = tid & 63;
    const int bh = blockIdx.y, b = bh >> 3, h = bh & 7;
    const int r = blockIdx.x * 4 + w;                 // query row in [0, S)
    const float* Kb = Kg + (size_t)bh * SSc * DKc;
    const float* Vb = Vg + (size_t)bh * SSc * DKc;

    if (tid < 2 * MMc + 1) { rks[tid] = rk_t[tid * HHc + h]; rbs[tid] = rb_t[tid * HHc + h]; }

    float q[DKc];
    {
        const float* Qr = Qg + ((size_t)bh * SSc + r) * DKc;
#pragma unroll
        for (int d = 0; d < DKc; ++d) q[d] = Qr[d];
    }
    const int pi = posg[b * SSc + r];
    float m = -INFINITY, l = 0.0f, o = 0.0f;          // o: lanes 0..31 own dim=lane

    __syncthreads();                                   // rks/rbs visible

    for (int j0 = 0; j0 < SSc; j0 += 64) {
        __syncthreads();
#pragma unroll
        for (int e = 0; e < 8; ++e) {                  // stage K & V tile (64x32)
            int idx = tid + e * 256;
            int rr = idx >> 5, d = idx & 31;
            Ks[rr][d] = Kb[(size_t)(j0 + rr) * DKc + d];
            Vs[rr][d] = Vb[(size_t)(j0 + rr) * DKc + d];
        }
        __syncthreads();
        float sv;
        {
            float acc = 0.0f;
#pragma unroll
            for (int d = 0; d < DKc; ++d) acc += q[d] * Ks[lane][d];
            const int pj = posg[b * SSc + j0 + lane];
            const int ridx = rel_index(pi, pj);
            sv = acc * ISQD * rks[ridx] + rbs[ridx];
            if (maskg[b * SSc + j0 + lane] == 0) sv = NEGF;
        }
        float tm = sv;
#pragma unroll
        for (int mk = 1; mk < 64; mk <<= 1) tm = fmaxf(tm, __shfl_xor(tm, mk));
        const float nm = fmaxf(m, tm);
        const float scale = expf(m - nm);
        const float p = expf(sv - nm);
        float ps = p;
#pragma unroll
        for (int mk = 1; mk < 64; mk <<= 1) ps += __shfl_xor(ps, mk);
        l = l * scale + ps;
        m = nm;
        Pr[w][lane] = p;
        o *= scale;
        __syncthreads();                               // Pr visible
        if (lane < DKc) {
#pragma unroll 8
            for (int jj = 0; jj < 64; ++jj) o += Pr[w][jj] * Vs[jj][lane];
        }
    }
    const float invl = 1.0f / l;
    if (lane < DKc)
        Ob[((size_t)b * SSc + r) * HDKc + h * DKc + lane] = o * invl;

    // pass 2: exact probabilities with final (m, l) -> f32 RMW into att
    for (int j0 = 0; j0 < SSc; j0 += 64) {
        __syncthreads();
#pragma unroll
        for (int e = 0; e < 8; ++e) {
            int idx = tid + e * 256;
            int rr = idx >> 5, d = idx & 31;
            Ks[rr][d] = Kb[(size_t)(j0 + rr) * DKc + d];
        }
        __syncthreads();
        float acc = 0.0f;
#pragma unroll
        for (int d = 0; d < DKc; ++d) acc += q[d] * Ks[lane][d];
        const int pj = posg[b * SSc + j0 + lane];
        const int ridx = rel_index(pi, pj);
        float sv = acc * ISQD * rks[ridx] + rbs[ridx];
        if (maskg[b * SSc + j0 + lane] == 0) sv = NEGF;
        const float p = expf(sv - m) * invl;
        float* ap = att + ((size_t)bh * SSc + r) * SSc + j0 + lane;
        const float outv = addmode ? (*ap + p) : p;
        *ap = outv * scalef;
    }
}

extern "C" void kernel_launch(void* const* d_in, const int* in_sizes, int n_in,
                              void* d_out, int out_size, void* d_ws, size_t ws_size,
                              hipStream_t stream)
{
    const size_t NF = (size_t)NRc * FFc;      // 1,048,576
    float* outx = (float*)d_out;
    float* att  = outx + NF;

    const size_t needed = 4 * NF * sizeof(float);
    if (ws_size < needed) { fill_f32<<<dim3(4096), dim3(256), 0, stream>>>(outx, 1000.0f); return; }

    const float* x0   = (const float*)d_in[0];
    const int*   mask = (const int*)d_in[1];
    const int*   pos  = (const int*)d_in[2];
    const float* Wq   = (const float*)d_in[3];
    const float* bq   = (const float*)d_in[4];
    const float* Wk   = (const float*)d_in[5];
    const float* bk   = (const float*)d_in[6];
    const float* Wv   = (const float*)d_in[7];
    const float* bv   = (const float*)d_in[8];
    const float* Wo   = (const float*)d_in[9];
    const float* bo   = (const float*)d_in[10];
    const float* relk = (const float*)d_in[11];
    const float* relb = (const float*)d_in[12];
    const float* ln1g = (const float*)d_in[13];
    const float* ln1b = (const float*)d_in[14];
    const float* W1   = (const float*)d_in[15];
    const float* b1   = (const float*)d_in[16];
    const float* W2   = (const float*)d_in[17];
    const float* b2   = (const float*)d_in[18];
    const float* ln2g = (const float*)d_in[19];
    const float* ln2b = (const float*)d_in[20];

    float* ws = (float*)d_ws;
    float* slot0 = ws;            // X (layer input) -> Ob
    float* slot1 = ws + 1 * NF;   // Q -> MD slab [1024 x 1024]
    float* slot2 = ws + 2 * NF;   // K -> T1 -> T2
    float* slot3 = ws + 3 * NF;   // V -> HB

    const dim3 blk(256);
    for (int l = 0; l < LLc; ++l) {
        const float* xin = l ? slot0 : x0;
        float* Q  = slot1;
        float* Kb = slot2;
        float* Vb = slot3;
        proj_qkv<<<dim3(4096), blk, 0, stream>>>(xin, Wq + (size_t)l * FFc * HDKc, bq + l * HDKc, Q);
        proj_qkv<<<dim3(4096), blk, 0, stream>>>(xin, Wk + (size_t)l * FFc * HDKc, bk + l * HDKc, Kb);
        proj_qkv<<<dim3(4096), blk, 0, stream>>>(xin, Wv + (size_t)l * FFc * HDKc, bv + l * HDKc, Vb);
        float* Ob = slot0;        // x dead after projections
        attn_naive<<<dim3(SSc / 4, BBc * HHc), blk, 0, stream>>>(
            Q, Kb, Vb, pos, mask,
            relk + l * (2 * MMc + 1) * HHc, relb + l * (2 * MMc + 1) * HHc,
            att, Ob, l > 0 ? 1 : 0, l == LLc - 1 ? 0.25f : 1.0f);
        float* T1 = slot2;        // K dead
        mm_naive<0, FFc, HDKc><<<dim3(NRc * FFc / 256), blk, 0, stream>>>(
            Ob, Wo + (size_t)l * HDKc * FFc, bo + l * FFc, T1);
        float* HB = slot3;        // V dead
        ln_kernel<false><<<NRc / 4, blk, 0, stream>>>(T1, ln1g + l * FFc, ln1b + l * FFc, HB, (float*)nullptr);
        float* MD = slot1;        // Q dead
        float* T2 = slot2;        // T1 consumed by LN1
        for (int c = 0; c < 4; ++c) {
            const float* hbC = HB + (size_t)c * 1024 * FFc;
            float*       t2C = T2 + (size_t)c * 1024 * FFc;
            mm_naive<2, F4c, FFc><<<dim3(1024 * F4c / 256), blk, 0, stream>>>(
                hbC, W1 + (size_t)l * FFc * F4c, b1 + l * F4c, MD);
            mm_naive<0, FFc, F4c><<<dim3(1024 * FFc / 256), blk, 0, stream>>>(
                MD, W2 + (size_t)l * F4c * FFc, b2 + l * FFc, t2C);
        }
        if (l == LLc - 1)
            ln_kernel<true><<<NRc / 4, blk, 0, stream>>>(T2, ln2g + l * FFc, ln2b + l * FFc, slot0, outx);
        else
            ln_kernel<false><<<NRc / 4, blk, 0, stream>>>(T2, ln2g + l * FFc, ln2b + l * FFc, slot0, (float*)nullptr);
    }
}

// Round 5
// 4304.657 us; speedup vs baseline: 2.2519x; 2.2519x over previous
//
#include <hip/hip_runtime.h>
#include <hip/hip_bf16.h>
#include <math.h>

#define LLc  4
#define BBc  2
#define SSc  2048
#define FFc  256
#define HHc  8
#define DKc  32
#define MMc  10
#define HDKc 256
#define F4c  1024
#define NRc  4096          /* B*S */
#define NEGF (-4294967295.0f)
#define ISQD 0.17677669529663687f  /* 1/sqrt(32) */

__device__ __forceinline__ int rel_index(int pi, int pj) {
    int dd = pi - pj; if (dd < 0) dd = -dd;
    if (dd <= MMc) return dd;
    int t = (int)(10.0f + log2f((float)(dd - MMc)));
    return t > 2 * MMc ? 2 * MMc : t;
}

__global__ __launch_bounds__(256)
void fill_f32(float* __restrict__ p, float v) {
    p[(size_t)blockIdx.x * 256 + threadIdx.x] = v;
}

// ---------------- tiled f32 GEMM: C[rows x Nc] = A[rows x Kd] @ Bw[Kd x Nc] + bias
// MODE 0: plain. MODE 1: scatter to [B,H,S,DK]. MODE 2: exact GELU.
template<int MODE>
__global__ __launch_bounds__(256)
void gemm_f32(const float* __restrict__ A, const float* __restrict__ Bw,
              const float* __restrict__ bias, float* __restrict__ C,
              int Nc, int Kd)
{
    __shared__ float As[16][68];   // k-major (transposed), padded
    __shared__ float Bs[16][64];
    const int tid = threadIdx.x;
    const int ti = tid >> 4, tj = tid & 15;
    const int i0 = blockIdx.y * 64, n0 = blockIdx.x * 64;
    float acc[4][4] = {};
    for (int k0 = 0; k0 < Kd; k0 += 16) {
#pragma unroll
        for (int e = 0; e < 4; ++e) {
            int idx = tid + e * 256;
            int k = idx & 15, r = idx >> 4;
            As[k][r] = A[(size_t)(i0 + r) * Kd + (k0 + k)];
        }
#pragma unroll
        for (int e = 0; e < 4; ++e) {
            int idx = tid + e * 256;
            int c = idx & 63, k = idx >> 6;
            Bs[k][c] = Bw[(size_t)(k0 + k) * Nc + (n0 + c)];
        }
        __syncthreads();
#pragma unroll
        for (int k = 0; k < 16; ++k) {
            const float4 av = *(const float4*)&As[k][ti * 4];
            const float4 bv = *(const float4*)&Bs[k][tj * 4];
            const float a0 = av.x, a1 = av.y, a2 = av.z, a3 = av.w;
            const float c0 = bv.x, c1 = bv.y, c2 = bv.z, c3 = bv.w;
            acc[0][0] += a0 * c0; acc[0][1] += a0 * c1; acc[0][2] += a0 * c2; acc[0][3] += a0 * c3;
            acc[1][0] += a1 * c0; acc[1][1] += a1 * c1; acc[1][2] += a1 * c2; acc[1][3] += a1 * c3;
            acc[2][0] += a2 * c0; acc[2][1] += a2 * c1; acc[2][2] += a2 * c2; acc[2][3] += a2 * c3;
            acc[3][0] += a3 * c0; acc[3][1] += a3 * c1; acc[3][2] += a3 * c2; acc[3][3] += a3 * c3;
        }
        __syncthreads();
    }
#pragma unroll
    for (int e = 0; e < 4; ++e) {
        const int r = i0 + ti * 4 + e;
#pragma unroll
        for (int f = 0; f < 4; ++f) {
            const int c = n0 + tj * 4 + f;
            float v = acc[e][f] + bias[c];
            if (MODE == 1) {
                const int b = r >> 11, s = r & (SSc - 1);
                const int h = c >> 5, d = c & 31;
                C[((size_t)(b * HHc + h) * SSc + s) * DKc + d] = v;
            } else if (MODE == 2) {
                C[(size_t)r * Nc + c] = 0.5f * v * (1.0f + erff(v * 0.70710678118654752f));
            } else {
                C[(size_t)r * Nc + c] = v;
            }
        }
    }
}

// ---------------- LayerNorm over F=256, one wave per row ----------------
template<bool FINAL>
__global__ __launch_bounds__(256)
void ln_kernel(const float* __restrict__ Xi, const float* __restrict__ g,
               const float* __restrict__ bia, float* __restrict__ Y,
               float* __restrict__ Yout)
{
    const int row = blockIdx.x * 4 + (threadIdx.x >> 6);
    const int lane = threadIdx.x & 63;
    const float4 v = *(const float4*)&Xi[(size_t)row * FFc + lane * 4];
    float s = v.x + v.y + v.z + v.w;
    float s2 = v.x * v.x + v.y * v.y + v.z * v.z + v.w * v.w;
#pragma unroll
    for (int m = 1; m < 64; m <<= 1) { s += __shfl_xor(s, m); s2 += __shfl_xor(s2, m); }
    const float mu = s * (1.0f / FFc);
    float var = s2 * (1.0f / FFc) - mu * mu;
    var = fmaxf(var, 0.0f);
    const float inv = 1.0f / sqrtf(var + 1e-5f);
    const float4 gv = *(const float4*)&g[lane * 4];
    const float4 bv = *(const float4*)&bia[lane * 4];
    float4 o;
    o.x = (v.x - mu) * inv * gv.x + bv.x;
    o.y = (v.y - mu) * inv * gv.y + bv.y;
    o.z = (v.z - mu) * inv * gv.z + bv.z;
    o.w = (v.w - mu) * inv * gv.w + bv.w;
    *(float4*)&Y[(size_t)row * FFc + lane * 4] = o;
    if (FINAL) {
        *(float4*)&Yout[(size_t)row * FFc + lane * 4] = o;
    }
}

// ---------------- fused tiled attention: one block = 64 query rows, 256 threads.
// Loop 1: l[row] = sum_j exp(s)  (no max subtraction: |s| < ~1, rel tables are 0.02-scale).
// Loop 2: p = exp(s)/l -> f32 RMW into att; P^T via LDS; PV micro-gemm -> Ob.
__global__ __launch_bounds__(256)
void attn_fused(const float* __restrict__ Qg, const float* __restrict__ Kg,
                const float* __restrict__ Vg,
                const int* __restrict__ posg, const int* __restrict__ maskg,
                const float* __restrict__ rk_t, const float* __restrict__ rb_t,
                float* __restrict__ att, float* __restrict__ Ob,
                int addmode, float scalef)
{
    __shared__ float Qs[DKc][68];
    __shared__ float Ks[DKc][68];
    __shared__ float Vs[64][DKc];
    __shared__ float Pst[64][68];
    __shared__ float rks[2 * MMc + 1], rbs[2 * MMc + 1];
    __shared__ int   pis[64], pjs[64], msks[64];
    __shared__ float ils[64];

    const int tid = threadIdx.x;
    const int bh = blockIdx.y;
    const int b = bh >> 3, h = bh & 7;
    const int i0 = blockIdx.x * 64;
    const float* Qb  = Qg + ((size_t)bh * SSc + i0) * DKc;
    const float* Kbb = Kg + (size_t)bh * SSc * DKc;
    const float* Vbb = Vg + (size_t)bh * SSc * DKc;

#pragma unroll
    for (int e = 0; e < 8; ++e) {           // stage Q tile transposed: Qs[d][i]
        int idx = tid + e * 256;
        int d = idx & 31, r = idx >> 5;
        Qs[d][r] = Qb[(size_t)r * DKc + d];
    }
    if (tid < 2 * MMc + 1) { rks[tid] = rk_t[tid * HHc + h]; rbs[tid] = rb_t[tid * HHc + h]; }
    if (tid < 64) pis[tid] = posg[b * SSc + i0 + tid];

    const int ti = tid >> 4, tj = tid & 15;       // score micro: 4 rows x 4 cols
    const int oi = tid & 15, od = (tid >> 4) * 2; // PV micro: 4 rows x 2 dims
    float lrun[4] = {0.0f, 0.0f, 0.0f, 0.0f};
    float Oa[4][2] = {};

    // ---------- loop 1: denominators ----------
    for (int j0 = 0; j0 < SSc; j0 += 64) {
        __syncthreads();
#pragma unroll
        for (int e = 0; e < 8; ++e) {       // stage K transposed
            int idx = tid + e * 256;
            int d = idx & 31, r = idx >> 5;
            Ks[d][r] = Kbb[(size_t)(j0 + r) * DKc + d];
        }
        if (tid < 64) {
            pjs[tid]  = posg[b * SSc + j0 + tid];
            msks[tid] = (maskg[b * SSc + j0 + tid] == 0);
        }
        __syncthreads();

        float acc[4][4] = {};
#pragma unroll
        for (int k = 0; k < DKc; ++k) {
            const float4 av = *(const float4*)&Qs[k][ti * 4];
            const float4 bv = *(const float4*)&Ks[k][tj * 4];
            acc[0][0] += av.x * bv.x; acc[0][1] += av.x * bv.y; acc[0][2] += av.x * bv.z; acc[0][3] += av.x * bv.w;
            acc[1][0] += av.y * bv.x; acc[1][1] += av.y * bv.y; acc[1][2] += av.y * bv.z; acc[1][3] += av.y * bv.w;
            acc[2][0] += av.z * bv.x; acc[2][1] += av.z * bv.y; acc[2][2] += av.z * bv.z; acc[2][3] += av.z * bv.w;
            acc[3][0] += av.w * bv.x; acc[3][1] += av.w * bv.y; acc[3][2] += av.w * bv.z; acc[3][3] += av.w * bv.w;
        }
#pragma unroll
        for (int e = 0; e < 4; ++e) {
            const int pi = pis[ti * 4 + e];
            float ps = 0.0f;
#pragma unroll
            for (int f = 0; f < 4; ++f) {
                const int ridx = rel_index(pi, pjs[tj * 4 + f]);
                float sv = acc[e][f] * ISQD * rks[ridx] + rbs[ridx];
                if (msks[tj * 4 + f]) sv = NEGF;
                ps += expf(sv);
            }
#pragma unroll
            for (int mk = 1; mk < 16; mk <<= 1) ps += __shfl_xor(ps, mk, 16);
            lrun[e] += ps;
        }
    }
    __syncthreads();
    if (tj == 0) {
#pragma unroll
        for (int e = 0; e < 4; ++e) ils[ti * 4 + e] = 1.0f / lrun[e];
    }

    // ---------- loop 2: probabilities, att RMW, PV ----------
    for (int j0 = 0; j0 < SSc; j0 += 64) {
        __syncthreads();
#pragma unroll
        for (int e = 0; e < 8; ++e) {       // stage K transposed and V
            int idx = tid + e * 256;
            int d = idx & 31, r = idx >> 5;
            Ks[d][r] = Kbb[(size_t)(j0 + r) * DKc + d];
            Vs[r][d] = Vbb[(size_t)(j0 + r) * DKc + d];
        }
        if (tid < 64) {
            pjs[tid]  = posg[b * SSc + j0 + tid];
            msks[tid] = (maskg[b * SSc + j0 + tid] == 0);
        }
        __syncthreads();

        float acc[4][4] = {};
#pragma unroll
        for (int k = 0; k < DKc; ++k) {
            const float4 av = *(const float4*)&Qs[k][ti * 4];
            const float4 bv = *(const float4*)&Ks[k][tj * 4];
            acc[0][0] += av.x * bv.x; acc[0][1] += av.x * bv.y; acc[0][2] += av.x * bv.z; acc[0][3] += av.x * bv.w;
            acc[1][0] += av.y * bv.x; acc[1][1] += av.y * bv.y; acc[1][2] += av.y * bv.z; acc[1][3] += av.y * bv.w;
            acc[2][0] += av.z * bv.x; acc[2][1] += av.z * bv.y; acc[2][2] += av.z * bv.z; acc[2][3] += av.z * bv.w;
            acc[3][0] += av.w * bv.x; acc[3][1] += av.w * bv.y; acc[3][2] += av.w * bv.z; acc[3][3] += av.w * bv.w;
        }
        float p[4][4];
#pragma unroll
        for (int e = 0; e < 4; ++e) {
            const int pi = pis[ti * 4 + e];
            const float il = ils[ti * 4 + e];
#pragma unroll
            for (int f = 0; f < 4; ++f) {
                const int ridx = rel_index(pi, pjs[tj * 4 + f]);
                float sv = acc[e][f] * ISQD * rks[ridx] + rbs[ridx];
                if (msks[tj * 4 + f]) sv = NEGF;
                p[e][f] = expf(sv) * il;
            }
        }
        // f32 RMW-accumulate attn into d_out
#pragma unroll
        for (int e = 0; e < 4; ++e) {
            float* ap = att + ((size_t)bh * SSc + (i0 + ti * 4 + e)) * SSc + (j0 + tj * 4);
            float4 st;
            if (addmode) {
                const float4 old = *(const float4*)ap;
                st.x = (old.x + p[e][0]) * scalef;
                st.y = (old.y + p[e][1]) * scalef;
                st.z = (old.z + p[e][2]) * scalef;
                st.w = (old.w + p[e][3]) * scalef;
            } else {
                st.x = p[e][0]; st.y = p[e][1]; st.z = p[e][2]; st.w = p[e][3];
            }
            *(float4*)ap = st;
        }
        // stash P^T for the PV micro-gemm
#pragma unroll
        for (int f = 0; f < 4; ++f) {
            float4 pc; pc.x = p[0][f]; pc.y = p[1][f]; pc.z = p[2][f]; pc.w = p[3][f];
            *(float4*)&Pst[tj * 4 + f][ti * 4] = pc;
        }
        __syncthreads();
#pragma unroll 4
        for (int jj = 0; jj < 64; ++jj) {
            const float4 pv = *(const float4*)&Pst[jj][oi * 4];
            const float2 vv = *(const float2*)&Vs[jj][od];
            Oa[0][0] += pv.x * vv.x; Oa[0][1] += pv.x * vv.y;
            Oa[1][0] += pv.y * vv.x; Oa[1][1] += pv.y * vv.y;
            Oa[2][0] += pv.z * vv.x; Oa[2][1] += pv.z * vv.y;
            Oa[3][0] += pv.w * vv.x; Oa[3][1] += pv.w * vv.y;
        }
    }

#pragma unroll
    for (int e = 0; e < 4; ++e) {
        const int gi = i0 + oi * 4 + e;
        float* op = Ob + ((size_t)b * SSc + gi) * HDKc + h * DKc + od;
        op[0] = Oa[e][0];
        op[1] = Oa[e][1];
    }
}

extern "C" void kernel_launch(void* const* d_in, const int* in_sizes, int n_in,
                              void* d_out, int out_size, void* d_ws, size_t ws_size,
                              hipStream_t stream)
{
    const size_t NF = (size_t)NRc * FFc;      // 1,048,576
    float* outx = (float*)d_out;
    float* att  = outx + NF;

    const size_t needed = 4 * NF * sizeof(float);
    if (ws_size < needed) { fill_f32<<<dim3(4096), dim3(256), 0, stream>>>(outx, 1000.0f); return; }

    const float* x0   = (const float*)d_in[0];
    const int*   mask = (const int*)d_in[1];
    const int*   pos  = (const int*)d_in[2];
    const float* Wq   = (const float*)d_in[3];
    const float* bq   = (const float*)d_in[4];
    const float* Wk   = (const float*)d_in[5];
    const float* bk   = (const float*)d_in[6];
    const float* Wv   = (const float*)d_in[7];
    const float* bv   = (const float*)d_in[8];
    const float* Wo   = (const float*)d_in[9];
    const float* bo   = (const float*)d_in[10];
    const float* relk = (const float*)d_in[11];
    const float* relb = (const float*)d_in[12];
    const float* ln1g = (const float*)d_in[13];
    const float* ln1b = (const float*)d_in[14];
    const float* W1   = (const float*)d_in[15];
    const float* b1   = (const float*)d_in[16];
    const float* W2   = (const float*)d_in[17];
    const float* b2   = (const float*)d_in[18];
    const float* ln2g = (const float*)d_in[19];
    const float* ln2b = (const float*)d_in[20];

    float* ws = (float*)d_ws;
    float* slot0 = ws;            // X (layer input) -> Ob
    float* slot1 = ws + 1 * NF;   // Q -> MD slab [1024 x 1024]
    float* slot2 = ws + 2 * NF;   // K -> T1 -> T2
    float* slot3 = ws + 3 * NF;   // V -> HB

    const dim3 blk(256);
    for (int l = 0; l < LLc; ++l) {
        const float* xin = l ? slot0 : x0;
        float* Q  = slot1;
        float* Kb = slot2;
        float* Vb = slot3;
        gemm_f32<1><<<dim3(4, 64), blk, 0, stream>>>(xin, Wq + (size_t)l * FFc * HDKc, bq + l * HDKc, Q,  HDKc, FFc);
        gemm_f32<1><<<dim3(4, 64), blk, 0, stream>>>(xin, Wk + (size_t)l * FFc * HDKc, bk + l * HDKc, Kb, HDKc, FFc);
        gemm_f32<1><<<dim3(4, 64), blk, 0, stream>>>(xin, Wv + (size_t)l * FFc * HDKc, bv + l * HDKc, Vb, HDKc, FFc);
        float* Ob = slot0;        // x dead after projections
        attn_fused<<<dim3(SSc / 64, BBc * HHc), blk, 0, stream>>>(
            Q, Kb, Vb, pos, mask,
            relk + l * (2 * MMc + 1) * HHc, relb + l * (2 * MMc + 1) * HHc,
            att, Ob, l > 0 ? 1 : 0, l == LLc - 1 ? 0.25f : 1.0f);
        float* T1 = slot2;        // K dead
        gemm_f32<0><<<dim3(4, 64), blk, 0, stream>>>(Ob, Wo + (size_t)l * HDKc * FFc, bo + l * FFc, T1, FFc, HDKc);
        float* HB = slot3;        // V dead
        ln_kernel<false><<<NRc / 4, blk, 0, stream>>>(T1, ln1g + l * FFc, ln1b + l * FFc, HB, (float*)nullptr);
        float* MD = slot1;        // Q dead
        float* T2 = slot2;        // T1 consumed
        for (int c = 0; c < 4; ++c) {
            const float* hbC = HB + (size_t)c * 1024 * FFc;
            float*       t2C = T2 + (size_t)c * 1024 * FFc;
            gemm_f32<2><<<dim3(16, 16), blk, 0, stream>>>(hbC, W1 + (size_t)l * FFc * F4c, b1 + l * F4c, MD, F4c, FFc);
            gemm_f32<0><<<dim3(4, 16), blk, 0, stream>>>(MD, W2 + (size_t)l * F4c * FFc, b2 + l * FFc, t2C, FFc, F4c);
        }
        if (l == LLc - 1)
            ln_kernel<true><<<NRc / 4, blk, 0, stream>>>(T2, ln2g + l * FFc, ln2b + l * FFc, slot0, outx);
        else
            ln_kernel<false><<<NRc / 4, blk, 0, stream>>>(T2, ln2g + l * FFc, ln2b + l * FFc, slot0, (float*)nullptr);
    }
}

// Round 6
// 2224.813 us; speedup vs baseline: 4.3570x; 1.9348x over previous
//
#include <hip/hip_runtime.h>
#include <hip/hip_bf16.h>
#include <math.h>

#define LLc  4
#define BBc  2
#define SSc  2048
#define FFc  256
#define HHc  8
#define DKc  32
#define MMc  10
#define HDKc 256
#define F4c  1024
#define NRc  4096          /* B*S */
#define NEGF (-4294967295.0f)
#define ISQD 0.17677669529663687f  /* 1/sqrt(32) */

typedef unsigned short u16;
typedef unsigned int   u32;
typedef __attribute__((ext_vector_type(8))) short short8;
typedef __attribute__((ext_vector_type(4))) float f32x4;

__device__ __forceinline__ u16 f2bf(float f) {
    u32 x; __builtin_memcpy(&x, &f, 4);
    x += 0x7FFFu + ((x >> 16) & 1u);   // round-to-nearest-even
    return (u16)(x >> 16);
}
__device__ __forceinline__ int rel_index(int pi, int pj) {
    int dd = pi - pj; if (dd < 0) dd = -dd;
    if (dd <= MMc) return dd;
    int t = (int)(10.0f + __log2f((float)(dd - MMc)));
    return t > 2 * MMc ? 2 * MMc : t;
}

__global__ __launch_bounds__(256)
void fill_f32(float* __restrict__ p, float v) {
    p[(size_t)blockIdx.x * 256 + threadIdx.x] = v;
}

// ---------------- tiled f32 GEMM: C[rows x Nc] = A[rows x Kd] @ Bw[Kd x Nc] + bias
// MODE 0: plain f32. MODE 1: bf16 scatter to [B,H,S,DK] with scale. MODE 2: exact GELU.
template<int MODE>
__global__ __launch_bounds__(256)
void gemm_f32(const float* __restrict__ A, const float* __restrict__ Bw,
              const float* __restrict__ bias, float* __restrict__ C,
              u16* __restrict__ Cb, float scale, int Nc, int Kd)
{
    __shared__ float As[16][68];   // k-major (transposed), padded
    __shared__ float Bs[16][64];
    const int tid = threadIdx.x;
    const int ti = tid >> 4, tj = tid & 15;
    const int i0 = blockIdx.y * 64, n0 = blockIdx.x * 64;
    float acc[4][4] = {};
    for (int k0 = 0; k0 < Kd; k0 += 16) {
#pragma unroll
        for (int e = 0; e < 4; ++e) {
            int idx = tid + e * 256;
            int k = idx & 15, r = idx >> 4;
            As[k][r] = A[(size_t)(i0 + r) * Kd + (k0 + k)];
        }
#pragma unroll
        for (int e = 0; e < 4; ++e) {
            int idx = tid + e * 256;
            int c = idx & 63, k = idx >> 6;
            Bs[k][c] = Bw[(size_t)(k0 + k) * Nc + (n0 + c)];
        }
        __syncthreads();
#pragma unroll
        for (int k = 0; k < 16; ++k) {
            const float4 av = *(const float4*)&As[k][ti * 4];
            const float4 bv = *(const float4*)&Bs[k][tj * 4];
            acc[0][0] += av.x * bv.x; acc[0][1] += av.x * bv.y; acc[0][2] += av.x * bv.z; acc[0][3] += av.x * bv.w;
            acc[1][0] += av.y * bv.x; acc[1][1] += av.y * bv.y; acc[1][2] += av.y * bv.z; acc[1][3] += av.y * bv.w;
            acc[2][0] += av.z * bv.x; acc[2][1] += av.z * bv.y; acc[2][2] += av.z * bv.z; acc[2][3] += av.z * bv.w;
            acc[3][0] += av.w * bv.x; acc[3][1] += av.w * bv.y; acc[3][2] += av.w * bv.z; acc[3][3] += av.w * bv.w;
        }
        __syncthreads();
    }
#pragma unroll
    for (int e = 0; e < 4; ++e) {
        const int r = i0 + ti * 4 + e;
        if (MODE == 1) {
            const int b = r >> 11, s = r & (SSc - 1);
            const int cbase = n0 + tj * 4;
            const int h = cbase >> 5, d0 = cbase & 31;
            ushort4 st;
            st.x = f2bf((acc[e][0] + bias[cbase + 0]) * scale);
            st.y = f2bf((acc[e][1] + bias[cbase + 1]) * scale);
            st.z = f2bf((acc[e][2] + bias[cbase + 2]) * scale);
            st.w = f2bf((acc[e][3] + bias[cbase + 3]) * scale);
            *(ushort4*)&Cb[((size_t)(b * HHc + h) * SSc + s) * DKc + d0] = st;
        } else {
#pragma unroll
            for (int f = 0; f < 4; ++f) {
                const int c = n0 + tj * 4 + f;
                float v = acc[e][f] + bias[c];
                if (MODE == 2) {
                    C[(size_t)r * Nc + c] = 0.5f * v * (1.0f + erff(v * 0.70710678118654752f));
                } else {
                    C[(size_t)r * Nc + c] = v;
                }
            }
        }
    }
}

// ---------------- LayerNorm over F=256, one wave per row ----------------
template<bool FINAL>
__global__ __launch_bounds__(256)
void ln_kernel(const float* __restrict__ Xi, const float* __restrict__ g,
               const float* __restrict__ bia, float* __restrict__ Y,
               float* __restrict__ Yout)
{
    const int row = blockIdx.x * 4 + (threadIdx.x >> 6);
    const int lane = threadIdx.x & 63;
    const float4 v = *(const float4*)&Xi[(size_t)row * FFc + lane * 4];
    float s = v.x + v.y + v.z + v.w;
    float s2 = v.x * v.x + v.y * v.y + v.z * v.z + v.w * v.w;
#pragma unroll
    for (int m = 1; m < 64; m <<= 1) { s += __shfl_xor(s, m); s2 += __shfl_xor(s2, m); }
    const float mu = s * (1.0f / FFc);
    float var = s2 * (1.0f / FFc) - mu * mu;
    var = fmaxf(var, 0.0f);
    const float inv = 1.0f / sqrtf(var + 1e-5f);
    const float4 gv = *(const float4*)&g[lane * 4];
    const float4 bv = *(const float4*)&bia[lane * 4];
    float4 o;
    o.x = (v.x - mu) * inv * gv.x + bv.x;
    o.y = (v.y - mu) * inv * gv.y + bv.y;
    o.z = (v.z - mu) * inv * gv.z + bv.z;
    o.w = (v.w - mu) * inv * gv.w + bv.w;
    *(float4*)&Y[(size_t)row * FFc + lane * 4] = o;
    if (FINAL) {
        *(float4*)&Yout[(size_t)row * FFc + lane * 4] = o;
    }
}

// ---------------- MFMA attention: block = 64 query rows (4 waves x 16), grid (32, B*H).
// Loop 1: per-row sum of exp(s) (no max subtraction; scores are rel-table-scaled, tiny).
// Loop 2: p = exp(s)/l -> f32 RMW into att; P^T (bf16) via per-wave LDS; PV MFMAs.
// MFMA layout note: A/B fragments use the consistent convention k=(lane>>4)*8+e for
// BOTH operands (any shared bijection gives a correct dot product); C/D layout is the
// HW-verified col=lane&15, row=(lane>>4)*4+reg.
__global__ __launch_bounds__(256)
void attn_mfma(const u16* __restrict__ Qbf, const u16* __restrict__ Kbf,
               const u16* __restrict__ Vbf,
               const int* __restrict__ posg, const int* __restrict__ maskg,
               const float* __restrict__ rk_t, const float* __restrict__ rb_t,
               float* __restrict__ att, float* __restrict__ Ob,
               int addmode, float scalef)
{
    __shared__ u16 Kl[64 * 40];          // K tile [64 j][32 k], row stride 40 (16B-aligned, ~2-way banks)
    __shared__ u16 Vt[32 * 72];          // V^T tile [32 d][64 j], stride 72
    __shared__ u16 Pst[4][16 * 80];      // per-wave P [16 i][64 j], stride 80
    __shared__ float rks[2 * MMc + 1], rbs[2 * MMc + 1];
    __shared__ int pjs[64], msks[64];

    const int tid = threadIdx.x;
    const int w = tid >> 6, lane = tid & 63;
    const int g = lane >> 4, c = lane & 15;
    const int bh = blockIdx.y, b = bh >> 3, h = bh & 7;
    const int i0 = blockIdx.x * 64;
    const int iw = i0 + w * 16;

    if (tid < 2 * MMc + 1) { rks[tid] = rk_t[tid * HHc + h]; rbs[tid] = rb_t[tid * HHc + h]; }

    // Q fragment (ISQD pre-folded by projection): row = c, k = g*8..g*8+7
    const short8 qf = *(const short8*)(Qbf + ((size_t)bh * SSc + iw + c) * DKc + g * 8);

    int pi[4];
#pragma unroll
    for (int r = 0; r < 4; ++r) pi[r] = posg[b * SSc + iw + g * 4 + r];

    float lrun[4] = {0.0f, 0.0f, 0.0f, 0.0f};

    // ---------- loop 1: denominators ----------
    for (int j0 = 0; j0 < SSc; j0 += 64) {
        __syncthreads();
        {
            const int j = tid >> 2, seg = tid & 3;
            *(short8*)&Kl[j * 40 + seg * 8] =
                *(const short8*)(Kbf + ((size_t)bh * SSc + j0 + j) * DKc + seg * 8);
            if (tid < 64) {
                pjs[tid]  = posg[b * SSc + j0 + tid];
                msks[tid] = (maskg[b * SSc + j0 + tid] == 0);
            }
        }
        __syncthreads();
#pragma unroll
        for (int jg = 0; jg < 4; ++jg) {
            const short8 kf = *(const short8*)&Kl[(jg * 16 + c) * 40 + g * 8];
            f32x4 sc = __builtin_amdgcn_mfma_f32_16x16x32_bf16(qf, kf, (f32x4){0.f, 0.f, 0.f, 0.f}, 0, 0, 0);
            const int pj = pjs[jg * 16 + c];
            const int mk = msks[jg * 16 + c];
#pragma unroll
            for (int r = 0; r < 4; ++r) {
                const int ridx = rel_index(pi[r], pj);
                float sv = sc[r] * rks[ridx] + rbs[ridx];
                sv = mk ? NEGF : sv;
                lrun[r] += __expf(sv);
            }
        }
    }
    float il[4];
#pragma unroll
    for (int r = 0; r < 4; ++r) {
        float t = lrun[r];
#pragma unroll
        for (int mk = 1; mk < 16; mk <<= 1) t += __shfl_xor(t, mk);
        il[r] = 1.0f / t;
    }

    f32x4 Of[2] = {{0.f, 0.f, 0.f, 0.f}, {0.f, 0.f, 0.f, 0.f}};

    // ---------- loop 2: probabilities, att RMW, PV ----------
    for (int j0 = 0; j0 < SSc; j0 += 64) {
        __syncthreads();
        {
            const int j = tid >> 2, seg = tid & 3;
            const short8 kv = *(const short8*)(Kbf + ((size_t)bh * SSc + j0 + j) * DKc + seg * 8);
            *(short8*)&Kl[j * 40 + seg * 8] = kv;
            const short8 vv = *(const short8*)(Vbf + ((size_t)bh * SSc + j0 + j) * DKc + seg * 8);
            const int d0 = seg * 8;
#pragma unroll
            for (int k = 0; k < 8; ++k) Vt[(d0 + k) * 72 + j] = (u16)vv[k];
            if (tid < 64) {
                pjs[tid]  = posg[b * SSc + j0 + tid];
                msks[tid] = (maskg[b * SSc + j0 + tid] == 0);
            }
        }
        __syncthreads();

        float pv[4][4];   // [r][jg]
#pragma unroll
        for (int jg = 0; jg < 4; ++jg) {
            const short8 kf = *(const short8*)&Kl[(jg * 16 + c) * 40 + g * 8];
            f32x4 sc = __builtin_amdgcn_mfma_f32_16x16x32_bf16(qf, kf, (f32x4){0.f, 0.f, 0.f, 0.f}, 0, 0, 0);
            const int pj = pjs[jg * 16 + c];
            const int mk = msks[jg * 16 + c];
#pragma unroll
            for (int r = 0; r < 4; ++r) {
                const int ridx = rel_index(pi[r], pj);
                float sv = sc[r] * rks[ridx] + rbs[ridx];
                sv = mk ? NEGF : sv;
                const float p = __expf(sv) * il[r];
                pv[r][jg] = p;
                Pst[w][(g * 4 + r) * 80 + jg * 16 + c] = f2bf(p);
            }
        }
        // f32 RMW-accumulate attn into d_out
#pragma unroll
        for (int r = 0; r < 4; ++r) {
            float* ap = att + ((size_t)bh * SSc + iw + g * 4 + r) * SSc + j0 + c;
#pragma unroll
            for (int jg = 0; jg < 4; ++jg) {
                float v = pv[r][jg];
                if (addmode) v += ap[jg * 16];
                ap[jg * 16] = v * scalef;
            }
        }
        // PV: P[16 x 64] @ V[64 x 32] via 4 MFMAs (2 j-chunks x 2 d-groups)
#pragma unroll
        for (int jc = 0; jc < 2; ++jc) {
            const short8 pf = *(const short8*)&Pst[w][c * 80 + jc * 32 + g * 8];
#pragma unroll
            for (int dg = 0; dg < 2; ++dg) {
                const short8 vf = *(const short8*)&Vt[(dg * 16 + c) * 72 + jc * 32 + g * 8];
                Of[dg] = __builtin_amdgcn_mfma_f32_16x16x32_bf16(pf, vf, Of[dg], 0, 0, 0);
            }
        }
    }

#pragma unroll
    for (int dg = 0; dg < 2; ++dg) {
#pragma unroll
        for (int r = 0; r < 4; ++r) {
            Ob[((size_t)b * SSc + iw + g * 4 + r) * HDKc + h * DKc + dg * 16 + c] = Of[dg][r];
        }
    }
}

extern "C" void kernel_launch(void* const* d_in, const int* in_sizes, int n_in,
                              void* d_out, int out_size, void* d_ws, size_t ws_size,
                              hipStream_t stream)
{
    const size_t NF = (size_t)NRc * FFc;      // 1,048,576
    float* outx = (float*)d_out;
    float* att  = outx + NF;

    const size_t needed = 4 * NF * sizeof(float);
    if (ws_size < needed) { fill_f32<<<dim3(4096), dim3(256), 0, stream>>>(outx, 1000.0f); return; }

    const float* x0   = (const float*)d_in[0];
    const int*   mask = (const int*)d_in[1];
    const int*   pos  = (const int*)d_in[2];
    const float* Wq   = (const float*)d_in[3];
    const float* bq   = (const float*)d_in[4];
    const float* Wk   = (const float*)d_in[5];
    const float* bk   = (const float*)d_in[6];
    const float* Wv   = (const float*)d_in[7];
    const float* bv   = (const float*)d_in[8];
    const float* Wo   = (const float*)d_in[9];
    const float* bo   = (const float*)d_in[10];
    const float* relk = (const float*)d_in[11];
    const float* relb = (const float*)d_in[12];
    const float* ln1g = (const float*)d_in[13];
    const float* ln1b = (const float*)d_in[14];
    const float* W1   = (const float*)d_in[15];
    const float* b1   = (const float*)d_in[16];
    const float* W2   = (const float*)d_in[17];
    const float* b2   = (const float*)d_in[18];
    const float* ln2g = (const float*)d_in[19];
    const float* ln2b = (const float*)d_in[20];

    float* ws = (float*)d_ws;
    float* slot0 = ws;            // X -> Ob -> MD(lo)
    float* slot1 = ws + 1 * NF;   // Qbf+Kbf (bf16) -> MD(hi)
    float* slot2 = ws + 2 * NF;   // Vbf (bf16) -> T1 -> T2
    float* slot3 = ws + 3 * NF;   // HB

    u16* Qbf = (u16*)slot1;       // NF bf16
    u16* Kbf = Qbf + NF;          // NF bf16
    u16* Vbf = (u16*)slot2;       // NF bf16

    const dim3 blk(256);
    for (int l = 0; l < LLc; ++l) {
        const float* xin = l ? slot0 : x0;
        gemm_f32<1><<<dim3(4, 64), blk, 0, stream>>>(xin, Wq + (size_t)l * FFc * HDKc, bq + l * HDKc,
                                                     nullptr, Qbf, ISQD, HDKc, FFc);
        gemm_f32<1><<<dim3(4, 64), blk, 0, stream>>>(xin, Wk + (size_t)l * FFc * HDKc, bk + l * HDKc,
                                                     nullptr, Kbf, 1.0f, HDKc, FFc);
        gemm_f32<1><<<dim3(4, 64), blk, 0, stream>>>(xin, Wv + (size_t)l * FFc * HDKc, bv + l * HDKc,
                                                     nullptr, Vbf, 1.0f, HDKc, FFc);
        float* Ob = slot0;        // X dead after projections
        attn_mfma<<<dim3(SSc / 64, BBc * HHc), blk, 0, stream>>>(
            Qbf, Kbf, Vbf, pos, mask,
            relk + l * (2 * MMc + 1) * HHc, relb + l * (2 * MMc + 1) * HHc,
            att, Ob, l > 0 ? 1 : 0, l == LLc - 1 ? 0.25f : 1.0f);
        float* T1 = slot2;        // Q/K/V dead
        gemm_f32<0><<<dim3(4, 64), blk, 0, stream>>>(Ob, Wo + (size_t)l * HDKc * FFc, bo + l * FFc,
                                                     T1, nullptr, 1.0f, FFc, HDKc);
        float* HB = slot3;
        ln_kernel<false><<<NRc / 4, blk, 0, stream>>>(T1, ln1g + l * FFc, ln1b + l * FFc, HB, (float*)nullptr);
        float* MD = slot0;        // 2048 x 1024 f32 spans slot0+slot1 (Ob, Qbf/Kbf dead)
        float* T2 = slot2;        // T1 dead after LN1
        for (int cch = 0; cch < 2; ++cch) {
            const float* hbC = HB + (size_t)cch * 2048 * FFc;
            float*       t2C = T2 + (size_t)cch * 2048 * FFc;
            gemm_f32<2><<<dim3(16, 32), blk, 0, stream>>>(hbC, W1 + (size_t)l * FFc * F4c, b1 + l * F4c,
                                                          MD, nullptr, 1.0f, F4c, FFc);
            gemm_f32<0><<<dim3(4, 32), blk, 0, stream>>>(MD, W2 + (size_t)l * F4c * FFc, b2 + l * FFc,
                                                         t2C, nullptr, 1.0f, FFc, F4c);
        }
        if (l == LLc - 1)
            ln_kernel<true><<<NRc / 4, blk, 0, stream>>>(T2, ln2g + l * FFc, ln2b + l * FFc, slot0, outx);
        else
            ln_kernel<false><<<NRc / 4, blk, 0, stream>>>(T2, ln2g + l * FFc, ln2b + l * FFc, slot0, (float*)nullptr);
    }
}

// Round 7
// 1601.792 us; speedup vs baseline: 6.0517x; 1.3890x over previous
//
#include <hip/hip_runtime.h>
#include <hip/hip_bf16.h>
#include <math.h>

#define LLc  4
#define BBc  2
#define SSc  2048
#define FFc  256
#define HHc  8
#define DKc  32
#define MMc  10
#define HDKc 256
#define F4c  1024
#define NRc  4096          /* B*S */
#define ISQD 0.17677669529663687f  /* 1/sqrt(32) */
#define LOG2E 1.4426950408889634f

typedef unsigned short u16;
typedef unsigned char  u8;
typedef unsigned int   u32;
typedef __attribute__((ext_vector_type(8))) short short8;
typedef __attribute__((ext_vector_type(4))) float f32x4;

__device__ __forceinline__ u16 f2bf(float f) {
    u32 x; __builtin_memcpy(&x, &f, 4);
    x += 0x7FFFu + ((x >> 16) & 1u);
    return (u16)(x >> 16);
}

__global__ __launch_bounds__(256)
void fill_f32(float* __restrict__ p, float v) {
    p[(size_t)blockIdx.x * 256 + threadIdx.x] = v;
}

// ---------------- rel index table: rel8[b][i][j], u8, layer-invariant ----------------
__global__ __launch_bounds__(256)
void build_rel8(const int* __restrict__ pos, u8* __restrict__ rel8)
{
    const int id = blockIdx.x * 256 + threadIdx.x;      // B*S*S/4 = 2,097,152
    const int j4 = id & (SSc / 4 - 1);
    const int i  = (id >> 9) & (SSc - 1);
    const int b  = id >> 20;
    const int pi = pos[b * SSc + i];
    uchar4 o;
    u8* po = (u8*)&o;
#pragma unroll
    for (int t = 0; t < 4; ++t) {
        const int pj = pos[b * SSc + j4 * 4 + t];
        int dd = pi - pj; if (dd < 0) dd = -dd;
        int ridx = dd;
        if (dd > MMc) {
            int v = (int)(10.0f + __log2f((float)(dd - MMc)));
            ridx = v > 2 * MMc ? 2 * MMc : v;
        }
        po[t] = (u8)ridx;
    }
    *(uchar4*)&rel8[(size_t)id * 4] = o;
}

// ---------------- bf16-MFMA GEMM: C[rows x Nc] = A[rows x Kd] @ W[Kd x Nc] + bias
// A,W are f32 in global, converted to bf16 during LDS staging; f32 accumulate.
// MODE 0: f32 out. MODE 1: bf16 scatter to [B,H,S,DK] with scale. MODE 2: f32 GELU out.
// SUMA: A_eff = A + A2 (elementwise, used to combine OPart halves).
template<int MODE, bool SUMA>
__global__ __launch_bounds__(256)
void gemm_mfma(const float* __restrict__ A, const float* __restrict__ A2,
               const float* __restrict__ W, const float* __restrict__ bias,
               float* __restrict__ C, u16* __restrict__ Cb, float scale,
               int Nc, int Kd)
{
    __shared__ u16 As[64][40];      // [row][k] bf16, stride 40 u16 (16B-aligned reads)
    __shared__ u16 Bt[64][40];      // [col][k] bf16
    const int tid = threadIdx.x;
    const int w = tid >> 6, lane = tid & 63;
    const int g = lane >> 4, c = lane & 15;
    const int i0 = blockIdx.y * 64, n0 = blockIdx.x * 64;
    const int srow = tid & 63, sk8 = (tid >> 6) * 8;

    f32x4 acc[4] = {{0.f,0.f,0.f,0.f},{0.f,0.f,0.f,0.f},{0.f,0.f,0.f,0.f},{0.f,0.f,0.f,0.f}};

    for (int k0 = 0; k0 < Kd; k0 += 32) {
        __syncthreads();
        {   // stage A rows (convert f32 -> bf16)
            const float* ap = A + (size_t)(i0 + srow) * Kd + k0 + sk8;
            float v[8];
            *(float4*)&v[0] = *(const float4*)&ap[0];
            *(float4*)&v[4] = *(const float4*)&ap[4];
            if (SUMA) {
                const float* ap2 = A2 + (size_t)(i0 + srow) * Kd + k0 + sk8;
                float u[8];
                *(float4*)&u[0] = *(const float4*)&ap2[0];
                *(float4*)&u[4] = *(const float4*)&ap2[4];
#pragma unroll
                for (int t = 0; t < 8; ++t) v[t] += u[t];
            }
            short8 st;
#pragma unroll
            for (int t = 0; t < 8; ++t) st[t] = (short)f2bf(v[t]);
            *(short8*)&As[srow][sk8] = st;
        }
        {   // stage B cols (transposed, convert)
            const float* wp = W + (size_t)(k0 + sk8) * Nc + n0 + srow;
            short8 st;
#pragma unroll
            for (int t = 0; t < 8; ++t) st[t] = (short)f2bf(wp[(size_t)t * Nc]);
            *(short8*)&Bt[srow][sk8] = st;
        }
        __syncthreads();
        const short8 af = *(const short8*)&As[w * 16 + c][g * 8];
#pragma unroll
        for (int nt = 0; nt < 4; ++nt) {
            const short8 bf = *(const short8*)&Bt[nt * 16 + c][g * 8];
            acc[nt] = __builtin_amdgcn_mfma_f32_16x16x32_bf16(af, bf, acc[nt], 0, 0, 0);
        }
    }

#pragma unroll
    for (int nt = 0; nt < 4; ++nt) {
        const int col = n0 + nt * 16 + c;
        const float bsv = bias[col];
#pragma unroll
        for (int r = 0; r < 4; ++r) {
            const int row = i0 + w * 16 + g * 4 + r;
            float v = acc[nt][r] + bsv;
            if (MODE == 1) {
                const int b = row >> 11, s = row & (SSc - 1);
                const int h = col >> 5, d = col & 31;
                Cb[((size_t)(b * HHc + h) * SSc + s) * DKc + d] = f2bf(v * scale);
            } else if (MODE == 2) {
                C[(size_t)row * Nc + col] = 0.5f * v * (1.0f + erff(v * 0.70710678118654752f));
            } else {
                C[(size_t)row * Nc + col] = v;
            }
        }
    }
}

// ---------------- LayerNorm over F=256, one wave per row ----------------
template<bool FINAL>
__global__ __launch_bounds__(256)
void ln_kernel(const float* __restrict__ Xi, const float* __restrict__ g,
               const float* __restrict__ bia, float* __restrict__ Y,
               float* __restrict__ Yout)
{
    const int row = blockIdx.x * 4 + (threadIdx.x >> 6);
    const int lane = threadIdx.x & 63;
    const float4 v = *(const float4*)&Xi[(size_t)row * FFc + lane * 4];
    float s = v.x + v.y + v.z + v.w;
    float s2 = v.x * v.x + v.y * v.y + v.z * v.z + v.w * v.w;
#pragma unroll
    for (int m = 1; m < 64; m <<= 1) { s += __shfl_xor(s, m); s2 += __shfl_xor(s2, m); }
    const float mu = s * (1.0f / FFc);
    float var = s2 * (1.0f / FFc) - mu * mu;
    var = fmaxf(var, 0.0f);
    const float inv = 1.0f / sqrtf(var + 1e-5f);
    const float4 gv = *(const float4*)&g[lane * 4];
    const float4 bv = *(const float4*)&bia[lane * 4];
    float4 o;
    o.x = (v.x - mu) * inv * gv.x + bv.x;
    o.y = (v.y - mu) * inv * gv.y + bv.y;
    o.z = (v.z - mu) * inv * gv.z + bv.z;
    o.w = (v.w - mu) * inv * gv.w + bv.w;
    *(float4*)&Y[(size_t)row * FFc + lane * 4] = o;
    if (FINAL) {
        *(float4*)&Yout[(size_t)row * FFc + lane * 4] = o;
    }
}

// ---------------- attention stats: partial softmax denominators over a j-half ----------
// grid (S/64, B*H, 2); block 256 (4 waves x 16 rows). Lpart[z][bh][s] = sum_j exp(s).
__global__ __launch_bounds__(256)
void attn_stats(const u16* __restrict__ Qbf, const u16* __restrict__ Kbf,
                const int* __restrict__ maskg, const u8* __restrict__ rel8,
                const float* __restrict__ rk_t, const float* __restrict__ rb_t,
                float* __restrict__ Lpart)
{
    __shared__ u16 Kl[64 * 40];
    __shared__ float rks2[2 * MMc + 1], rbs2[2 * MMc + 1];
    __shared__ int msks[64];

    const int tid = threadIdx.x;
    const int w = tid >> 6, lane = tid & 63;
    const int g = lane >> 4, c = lane & 15;
    const int bh = blockIdx.y, b = bh >> 3, h = bh & 7;
    const int z = blockIdx.z;
    const int iw = blockIdx.x * 64 + w * 16;

    if (tid < 2 * MMc + 1) {
        rks2[tid] = rk_t[tid * HHc + h] * LOG2E;
        rbs2[tid] = rb_t[tid * HHc + h] * LOG2E;
    }
    const short8 qf = *(const short8*)(Qbf + ((size_t)bh * SSc + iw + c) * DKc + g * 8);
    const u8* rp[4];
#pragma unroll
    for (int r = 0; r < 4; ++r) rp[r] = rel8 + ((size_t)b * SSc + iw + g * 4 + r) * SSc;

    float lrun[4] = {0.f, 0.f, 0.f, 0.f};
    const int jbeg = z * (SSc / 2), jend = jbeg + SSc / 2;
    for (int j0 = jbeg; j0 < jend; j0 += 64) {
        __syncthreads();
        {
            const int j = tid >> 2, seg = tid & 3;
            *(short8*)&Kl[j * 40 + seg * 8] =
                *(const short8*)(Kbf + ((size_t)bh * SSc + j0 + j) * DKc + seg * 8);
            if (tid < 64) msks[tid] = (maskg[b * SSc + j0 + tid] == 0);
        }
        __syncthreads();
#pragma unroll
        for (int jg = 0; jg < 4; ++jg) {
            const short8 kf = *(const short8*)&Kl[(jg * 16 + c) * 40 + g * 8];
            f32x4 sc = __builtin_amdgcn_mfma_f32_16x16x32_bf16(qf, kf, (f32x4){0.f,0.f,0.f,0.f}, 0, 0, 0);
            const int mk = msks[jg * 16 + c];
#pragma unroll
            for (int r = 0; r < 4; ++r) {
                const u8 rl = rp[r][j0 + jg * 16 + c];
                float sv = fmaf(sc[r], rks2[rl], rbs2[rl]);
                sv = mk ? -1e30f : sv;
                lrun[r] += exp2f(sv);
            }
        }
    }
#pragma unroll
    for (int r = 0; r < 4; ++r) {
#pragma unroll
        for (int mk = 1; mk < 16; mk <<= 1) lrun[r] += __shfl_xor(lrun[r], mk);
    }
    if (c == 0) {
#pragma unroll
        for (int r = 0; r < 4; ++r)
            Lpart[((size_t)z * BBc * HHc + bh) * SSc + iw + g * 4 + r] = lrun[r];
    }
}

__global__ __launch_bounds__(256)
void combine_l(const float* __restrict__ Lpart, float* __restrict__ RI)
{
    const int i = blockIdx.x * 256 + threadIdx.x;   // BH*S = 32768
    RI[i] = 1.0f / (Lpart[i] + Lpart[i + BBc * HHc * SSc]);
}

// ---------------- attention probs: p -> att RMW + partial PV over a j-half ------------
__global__ __launch_bounds__(256)
void attn_probs(const u16* __restrict__ Qbf, const u16* __restrict__ Kbf,
                const u16* __restrict__ Vbf,
                const int* __restrict__ maskg, const u8* __restrict__ rel8,
                const float* __restrict__ rk_t, const float* __restrict__ rb_t,
                const float* __restrict__ RI,
                float* __restrict__ att, float* __restrict__ OPart,
                int addmode, float scalef)
{
    __shared__ u16 Kl[64 * 40];
    __shared__ u16 Vt[32 * 72];
    __shared__ u16 Pst[4][16 * 88];
    __shared__ float rks2[2 * MMc + 1], rbs2[2 * MMc + 1];
    __shared__ int msks[64];

    const int tid = threadIdx.x;
    const int w = tid >> 6, lane = tid & 63;
    const int g = lane >> 4, c = lane & 15;
    const int bh = blockIdx.y, b = bh >> 3, h = bh & 7;
    const int z = blockIdx.z;
    const int iw = blockIdx.x * 64 + w * 16;

    if (tid < 2 * MMc + 1) {
        rks2[tid] = rk_t[tid * HHc + h] * LOG2E;
        rbs2[tid] = rb_t[tid * HHc + h] * LOG2E;
    }
    const short8 qf = *(const short8*)(Qbf + ((size_t)bh * SSc + iw + c) * DKc + g * 8);
    const u8* rp[4];
    float ri[4];
#pragma unroll
    for (int r = 0; r < 4; ++r) {
        rp[r] = rel8 + ((size_t)b * SSc + iw + g * 4 + r) * SSc;
        ri[r] = RI[(size_t)bh * SSc + iw + g * 4 + r];
    }

    f32x4 Of[2] = {{0.f,0.f,0.f,0.f}, {0.f,0.f,0.f,0.f}};
    const int jbeg = z * (SSc / 2), jend = jbeg + SSc / 2;
    for (int j0 = jbeg; j0 < jend; j0 += 64) {
        __syncthreads();
        {
            const int j = tid >> 2, seg = tid & 3;
            *(short8*)&Kl[j * 40 + seg * 8] =
                *(const short8*)(Kbf + ((size_t)bh * SSc + j0 + j) * DKc + seg * 8);
            const short8 vv = *(const short8*)(Vbf + ((size_t)bh * SSc + j0 + j) * DKc + seg * 8);
            const int d0 = seg * 8;
#pragma unroll
            for (int k = 0; k < 8; ++k) Vt[(d0 + k) * 72 + j] = (u16)vv[k];
            if (tid < 64) msks[tid] = (maskg[b * SSc + j0 + tid] == 0);
        }
        __syncthreads();

        float pv[4][4];
#pragma unroll
        for (int jg = 0; jg < 4; ++jg) {
            const short8 kf = *(const short8*)&Kl[(jg * 16 + c) * 40 + g * 8];
            f32x4 sc = __builtin_amdgcn_mfma_f32_16x16x32_bf16(qf, kf, (f32x4){0.f,0.f,0.f,0.f}, 0, 0, 0);
            const int mk = msks[jg * 16 + c];
#pragma unroll
            for (int r = 0; r < 4; ++r) {
                const u8 rl = rp[r][j0 + jg * 16 + c];
                float sv = fmaf(sc[r], rks2[rl], rbs2[rl]);
                sv = mk ? -1e30f : sv;
                const float p = exp2f(sv) * ri[r];
                pv[r][jg] = p;
                Pst[w][(g * 4 + r) * 88 + jg * 16 + c] = f2bf(p);
            }
        }
#pragma unroll
        for (int r = 0; r < 4; ++r) {
            float* ap = att + ((size_t)bh * SSc + iw + g * 4 + r) * SSc + j0 + c;
#pragma unroll
            for (int jg = 0; jg < 4; ++jg) {
                float v = pv[r][jg];
                if (addmode) v += ap[jg * 16];
                ap[jg * 16] = v * scalef;
            }
        }
#pragma unroll
        for (int jc = 0; jc < 2; ++jc) {
            const short8 pf = *(const short8*)&Pst[w][c * 88 + jc * 32 + g * 8];
#pragma unroll
            for (int dg = 0; dg < 2; ++dg) {
                const short8 vf = *(const short8*)&Vt[(dg * 16 + c) * 72 + jc * 32 + g * 8];
                Of[dg] = __builtin_amdgcn_mfma_f32_16x16x32_bf16(pf, vf, Of[dg], 0, 0, 0);
            }
        }
    }

#pragma unroll
    for (int dg = 0; dg < 2; ++dg) {
#pragma unroll
        for (int r = 0; r < 4; ++r) {
            OPart[(size_t)z * NRc * HDKc +
                  ((size_t)b * SSc + iw + g * 4 + r) * HDKc + h * DKc + dg * 16 + c] = Of[dg][r];
        }
    }
}

extern "C" void kernel_launch(void* const* d_in, const int* in_sizes, int n_in,
                              void* d_out, int out_size, void* d_ws, size_t ws_size,
                              hipStream_t stream)
{
    const size_t NF = (size_t)NRc * FFc;      // 1,048,576
    float* outx = (float*)d_out;
    float* att  = outx + NF;

    const size_t needed = (8 * NF + 131072) * sizeof(float);   // ~34 MB
    if (ws_size < needed) { fill_f32<<<dim3(4096), dim3(256), 0, stream>>>(outx, 1000.0f); return; }

    const float* x0   = (const float*)d_in[0];
    const int*   mask = (const int*)d_in[1];
    const int*   pos  = (const int*)d_in[2];
    const float* Wq   = (const float*)d_in[3];
    const float* bq   = (const float*)d_in[4];
    const float* Wk   = (const float*)d_in[5];
    const float* bk   = (const float*)d_in[6];
    const float* Wv   = (const float*)d_in[7];
    const float* bv   = (const float*)d_in[8];
    const float* Wo   = (const float*)d_in[9];
    const float* bo   = (const float*)d_in[10];
    const float* relk = (const float*)d_in[11];
    const float* relb = (const float*)d_in[12];
    const float* ln1g = (const float*)d_in[13];
    const float* ln1b = (const float*)d_in[14];
    const float* W1   = (const float*)d_in[15];
    const float* b1   = (const float*)d_in[16];
    const float* W2   = (const float*)d_in[17];
    const float* b2   = (const float*)d_in[18];
    const float* ln2g = (const float*)d_in[19];
    const float* ln2b = (const float*)d_in[20];

    float* ws = (float*)d_ws;
    float* slot0 = ws;            // X / MD(lo)
    float* slot1 = ws + 1 * NF;   // Qbf+Kbf / MD(hi)
    float* slot2 = ws + 2 * NF;   // Vbf / T1 / T2
    float* slot3 = ws + 3 * NF;   // HB
    u8*    rel8  = (u8*)(ws + 4 * NF);    // 2NF f32 worth = 8.4 MB
    float* OPart = ws + 6 * NF;           // 2 x NF
    float* Lpart = ws + 8 * NF;           // 2 x 32768
    float* RI    = ws + 8 * NF + 65536;   // 32768

    u16* Qbf = (u16*)slot1;
    u16* Kbf = Qbf + NF;
    u16* Vbf = (u16*)slot2;

    const dim3 blk(256);
    build_rel8<<<dim3(8192), blk, 0, stream>>>(pos, rel8);

    for (int l = 0; l < LLc; ++l) {
        const float* xin = l ? slot0 : x0;
        gemm_mfma<1, false><<<dim3(4, 64), blk, 0, stream>>>(xin, nullptr,
            Wq + (size_t)l * FFc * HDKc, bq + l * HDKc, nullptr, Qbf, ISQD, HDKc, FFc);
        gemm_mfma<1, false><<<dim3(4, 64), blk, 0, stream>>>(xin, nullptr,
            Wk + (size_t)l * FFc * HDKc, bk + l * HDKc, nullptr, Kbf, 1.0f, HDKc, FFc);
        gemm_mfma<1, false><<<dim3(4, 64), blk, 0, stream>>>(xin, nullptr,
            Wv + (size_t)l * FFc * HDKc, bv + l * HDKc, nullptr, Vbf, 1.0f, HDKc, FFc);

        attn_stats<<<dim3(SSc / 64, BBc * HHc, 2), blk, 0, stream>>>(
            Qbf, Kbf, mask, rel8,
            relk + l * (2 * MMc + 1) * HHc, relb + l * (2 * MMc + 1) * HHc, Lpart);
        combine_l<<<dim3(BBc * HHc * SSc / 256), blk, 0, stream>>>(Lpart, RI);
        attn_probs<<<dim3(SSc / 64, BBc * HHc, 2), blk, 0, stream>>>(
            Qbf, Kbf, Vbf, mask, rel8,
            relk + l * (2 * MMc + 1) * HHc, relb + l * (2 * MMc + 1) * HHc, RI,
            att, OPart, l > 0 ? 1 : 0, l == LLc - 1 ? 0.25f : 1.0f);

        float* T1 = slot2;        // V dead
        gemm_mfma<0, true><<<dim3(4, 64), blk, 0, stream>>>(OPart, OPart + NRc * HDKc,
            Wo + (size_t)l * HDKc * FFc, bo + l * FFc, T1, nullptr, 1.0f, FFc, HDKc);
        float* HB = slot3;
        ln_kernel<false><<<NRc / 4, blk, 0, stream>>>(T1, ln1g + l * FFc, ln1b + l * FFc, HB, (float*)nullptr);
        float* MD = slot0;        // X dead; MD spans slot0+slot1 chunked by rows
        float* T2 = slot2;
        for (int cch = 0; cch < 2; ++cch) {
            const float* hbC = HB + (size_t)cch * 2048 * FFc;
            float*       t2C = T2 + (size_t)cch * 2048 * FFc;
            gemm_mfma<2, false><<<dim3(16, 32), blk, 0, stream>>>(hbC, nullptr,
                W1 + (size_t)l * FFc * F4c, b1 + l * F4c, MD, nullptr, 1.0f, F4c, FFc);
            gemm_mfma<0, false><<<dim3(4, 32), blk, 0, stream>>>(MD, nullptr,
                W2 + (size_t)l * F4c * FFc, b2 + l * FFc, t2C, nullptr, 1.0f, FFc, F4c);
        }
        if (l == LLc - 1)
            ln_kernel<true><<<NRc / 4, blk, 0, stream>>>(T2, ln2g + l * FFc, ln2b + l * FFc, slot0, outx);
        else
            ln_kernel<false><<<NRc / 4, blk, 0, stream>>>(T2, ln2g + l * FFc, ln2b + l * FFc, slot0, (float*)nullptr);
    }
}

// Round 8
// 1484.082 us; speedup vs baseline: 6.5317x; 1.0793x over previous
//
#include <hip/hip_runtime.h>
#include <hip/hip_bf16.h>
#include <math.h>

#define LLc  4
#define BBc  2
#define SSc  2048
#define FFc  256
#define HHc  8
#define DKc  32
#define MMc  10
#define HDKc 256
#define F4c  1024
#define NRc  4096          /* B*S */
#define ISQD 0.17677669529663687f  /* 1/sqrt(32) */
#define LOG2E 1.4426950408889634f
#define ZSP  4             /* j-split */

typedef unsigned short u16;
typedef unsigned char  u8;
typedef unsigned int   u32;
typedef __attribute__((ext_vector_type(8))) short short8;
typedef __attribute__((ext_vector_type(4))) float f32x4;

__device__ __forceinline__ u16 f2bf(float f) {
    u32 x; __builtin_memcpy(&x, &f, 4);
    x += 0x7FFFu + ((x >> 16) & 1u);
    return (u16)(x >> 16);
}

__global__ __launch_bounds__(256)
void fill_f32(float* __restrict__ p, float v) {
    p[(size_t)blockIdx.x * 256 + threadIdx.x] = v;
}

// ---------------- rel index table: rel8[b][i][j], u8, layer-invariant ----------------
__global__ __launch_bounds__(256)
void build_rel8(const int* __restrict__ pos, u8* __restrict__ rel8)
{
    const int id = blockIdx.x * 256 + threadIdx.x;      // B*S*S/4
    const int j4 = id & (SSc / 4 - 1);
    const int i  = (id >> 9) & (SSc - 1);
    const int b  = id >> 20;
    const int pi = pos[b * SSc + i];
    uchar4 o;
    u8* po = (u8*)&o;
#pragma unroll
    for (int t = 0; t < 4; ++t) {
        const int pj = pos[b * SSc + j4 * 4 + t];
        int dd = pi - pj; if (dd < 0) dd = -dd;
        int ridx = dd;
        if (dd > MMc) {
            int v = (int)(10.0f + __log2f((float)(dd - MMc)));
            ridx = v > 2 * MMc ? 2 * MMc : v;
        }
        po[t] = (u8)ridx;
    }
    *(uchar4*)&rel8[(size_t)id * 4] = o;
}

// ---------------- bf16-MFMA GEMM: C[rows x Nc] = A_eff[rows x Kd] @ W[Kd x Nc] + bias
// A_eff = sum_{t<NSUM} A[t*Astride .. ]. MODE 0: f32 out. MODE 1: bf16 heads-scatter
// with scale. MODE 2: f32 GELU out.
template<int MODE, int NSUM>
__global__ __launch_bounds__(256)
void gemm_mfma(const float* __restrict__ A, size_t Astride,
               const float* __restrict__ W, const float* __restrict__ bias,
               float* __restrict__ C, u16* __restrict__ Cb, float scale,
               int Nc, int Kd)
{
    __shared__ u16 As[64][40];
    __shared__ u16 Bt[64][40];
    const int tid = threadIdx.x;
    const int w = tid >> 6, lane = tid & 63;
    const int g = lane >> 4, c = lane & 15;
    const int i0 = blockIdx.y * 64, n0 = blockIdx.x * 64;
    const int srow = tid & 63, sk8 = (tid >> 6) * 8;

    f32x4 acc[4] = {{0.f,0.f,0.f,0.f},{0.f,0.f,0.f,0.f},{0.f,0.f,0.f,0.f},{0.f,0.f,0.f,0.f}};

    for (int k0 = 0; k0 < Kd; k0 += 32) {
        __syncthreads();
        {
            const float* ap = A + (size_t)(i0 + srow) * Kd + k0 + sk8;
            float v[8];
            *(float4*)&v[0] = *(const float4*)&ap[0];
            *(float4*)&v[4] = *(const float4*)&ap[4];
#pragma unroll
            for (int t = 1; t < NSUM; ++t) {
                const float* ap2 = ap + (size_t)t * Astride;
                float u[8];
                *(float4*)&u[0] = *(const float4*)&ap2[0];
                *(float4*)&u[4] = *(const float4*)&ap2[4];
#pragma unroll
                for (int e = 0; e < 8; ++e) v[e] += u[e];
            }
            short8 st;
#pragma unroll
            for (int t = 0; t < 8; ++t) st[t] = (short)f2bf(v[t]);
            *(short8*)&As[srow][sk8] = st;
        }
        {
            const float* wp = W + (size_t)(k0 + sk8) * Nc + n0 + srow;
            short8 st;
#pragma unroll
            for (int t = 0; t < 8; ++t) st[t] = (short)f2bf(wp[(size_t)t * Nc]);
            *(short8*)&Bt[srow][sk8] = st;
        }
        __syncthreads();
        const short8 af = *(const short8*)&As[w * 16 + c][g * 8];
#pragma unroll
        for (int nt = 0; nt < 4; ++nt) {
            const short8 bf = *(const short8*)&Bt[nt * 16 + c][g * 8];
            acc[nt] = __builtin_amdgcn_mfma_f32_16x16x32_bf16(af, bf, acc[nt], 0, 0, 0);
        }
    }

#pragma unroll
    for (int nt = 0; nt < 4; ++nt) {
        const int col = n0 + nt * 16 + c;
        const float bsv = bias[col];
#pragma unroll
        for (int r = 0; r < 4; ++r) {
            const int row = i0 + w * 16 + g * 4 + r;
            float v = acc[nt][r] + bsv;
            if (MODE == 1) {
                const int b = row >> 11, s = row & (SSc - 1);
                const int h = col >> 5, d = col & 31;
                Cb[((size_t)(b * HHc + h) * SSc + s) * DKc + d] = f2bf(v * scale);
            } else if (MODE == 2) {
                C[(size_t)row * Nc + col] = 0.5f * v * (1.0f + erff(v * 0.70710678118654752f));
            } else {
                C[(size_t)row * Nc + col] = v;
            }
        }
    }
}

// ---------------- LayerNorm over F=256, one wave per row ----------------
template<bool FINAL>
__global__ __launch_bounds__(256)
void ln_kernel(const float* __restrict__ Xi, const float* __restrict__ g,
               const float* __restrict__ bia, float* __restrict__ Y,
               float* __restrict__ Yout)
{
    const int row = blockIdx.x * 4 + (threadIdx.x >> 6);
    const int lane = threadIdx.x & 63;
    const float4 v = *(const float4*)&Xi[(size_t)row * FFc + lane * 4];
    float s = v.x + v.y + v.z + v.w;
    float s2 = v.x * v.x + v.y * v.y + v.z * v.z + v.w * v.w;
#pragma unroll
    for (int m = 1; m < 64; m <<= 1) { s += __shfl_xor(s, m); s2 += __shfl_xor(s2, m); }
    const float mu = s * (1.0f / FFc);
    float var = s2 * (1.0f / FFc) - mu * mu;
    var = fmaxf(var, 0.0f);
    const float inv = 1.0f / sqrtf(var + 1e-5f);
    const float4 gv = *(const float4*)&g[lane * 4];
    const float4 bv = *(const float4*)&bia[lane * 4];
    float4 o;
    o.x = (v.x - mu) * inv * gv.x + bv.x;
    o.y = (v.y - mu) * inv * gv.y + bv.y;
    o.z = (v.z - mu) * inv * gv.z + bv.z;
    o.w = (v.w - mu) * inv * gv.w + bv.w;
    *(float4*)&Y[(size_t)row * FFc + lane * 4] = o;
    if (FINAL) {
        *(float4*)&Yout[(size_t)row * FFc + lane * 4] = o;
    }
}

// ---------------- attention stats (swapped orientation): Lpart over a j-quarter -------
// mfma(K,Q): lane (g,c) reg r -> score(query iw+c, j = j0+jg*16+g*4+r).
__global__ __launch_bounds__(256)
void attn_stats(const u16* __restrict__ Qbf, const u16* __restrict__ Kbf,
                const int* __restrict__ maskg, const u8* __restrict__ rel8,
                const float* __restrict__ rk_t, const float* __restrict__ rb_t,
                float* __restrict__ Lpart)
{
    __shared__ u16 Kl[64 * 40];
    __shared__ float rks2[2 * MMc + 1], rbs2[2 * MMc + 1];
    __shared__ u8 msks8[64];

    const int tid = threadIdx.x;
    const int w = tid >> 6, lane = tid & 63;
    const int g = lane >> 4, c = lane & 15;
    const int bh = blockIdx.y, b = bh >> 3, h = bh & 7;
    const int z = blockIdx.z;
    const int iw = blockIdx.x * 64 + w * 16;

    if (tid < 2 * MMc + 1) {
        rks2[tid] = rk_t[tid * HHc + h] * LOG2E;
        rbs2[tid] = rb_t[tid * HHc + h] * LOG2E;
    }
    const short8 qf = *(const short8*)(Qbf + ((size_t)bh * SSc + iw + c) * DKc + g * 8);
    const u8* relrow = rel8 + ((size_t)b * SSc + iw + c) * SSc;

    float lrun = 0.f;
    const int jbeg = z * (SSc / ZSP), jend = jbeg + SSc / ZSP;
    for (int j0 = jbeg; j0 < jend; j0 += 64) {
        __syncthreads();
        {
            const int j = tid >> 2, seg = tid & 3;
            *(short8*)&Kl[j * 40 + seg * 8] =
                *(const short8*)(Kbf + ((size_t)bh * SSc + j0 + j) * DKc + seg * 8);
            if (tid < 64) msks8[tid] = (u8)(maskg[b * SSc + j0 + tid] == 0);
        }
        __syncthreads();
#pragma unroll
        for (int jg = 0; jg < 4; ++jg) {
            const short8 kf = *(const short8*)&Kl[(jg * 16 + c) * 40 + g * 8];
            f32x4 sc = __builtin_amdgcn_mfma_f32_16x16x32_bf16(kf, qf, (f32x4){0.f,0.f,0.f,0.f}, 0, 0, 0);
            const uchar4 rl4 = *(const uchar4*)&relrow[j0 + jg * 16 + g * 4];
            const uchar4 mk4 = *(const uchar4*)&msks8[jg * 16 + g * 4];
            const u8* rl = (const u8*)&rl4;
            const u8* mk = (const u8*)&mk4;
#pragma unroll
            for (int r = 0; r < 4; ++r) {
                float sv = fmaf(sc[r], rks2[rl[r]], rbs2[rl[r]]);
                sv = mk[r] ? -1e30f : sv;
                lrun += exp2f(sv);
            }
        }
    }
    lrun += __shfl_xor(lrun, 16);
    lrun += __shfl_xor(lrun, 32);
    if (g == 0)
        Lpart[((size_t)z * BBc * HHc + bh) * SSc + iw + c] = lrun;
}

__global__ __launch_bounds__(256)
void combine_l(const float* __restrict__ Lpart, float* __restrict__ RI)
{
    const int i = blockIdx.x * 256 + threadIdx.x;   // BH*S = 32768
    float s = 0.f;
#pragma unroll
    for (int z = 0; z < ZSP; ++z) s += Lpart[(size_t)z * BBc * HHc * SSc + i];
    RI[i] = 1.0f / s;
}

// ---------------- attention probs (swapped): float4 att RMW + partial PV --------------
__global__ __launch_bounds__(256)
void attn_probs(const u16* __restrict__ Qbf, const u16* __restrict__ Kbf,
                const u16* __restrict__ Vbf,
                const int* __restrict__ maskg, const u8* __restrict__ rel8,
                const float* __restrict__ rk_t, const float* __restrict__ rb_t,
                const float* __restrict__ RI,
                float* __restrict__ att, float* __restrict__ OPart,
                int addmode, float scalef)
{
    __shared__ u16 Kl[64 * 40];
    __shared__ u16 Vt[32 * 72];
    __shared__ u16 Pst[4][16 * 72];
    __shared__ float rks2[2 * MMc + 1], rbs2[2 * MMc + 1];
    __shared__ u8 msks8[64];

    const int tid = threadIdx.x;
    const int w = tid >> 6, lane = tid & 63;
    const int g = lane >> 4, c = lane & 15;
    const int bh = blockIdx.y, b = bh >> 3, h = bh & 7;
    const int z = blockIdx.z;
    const int iw = blockIdx.x * 64 + w * 16;

    if (tid < 2 * MMc + 1) {
        rks2[tid] = rk_t[tid * HHc + h] * LOG2E;
        rbs2[tid] = rb_t[tid * HHc + h] * LOG2E;
    }
    const short8 qf = *(const short8*)(Qbf + ((size_t)bh * SSc + iw + c) * DKc + g * 8);
    const u8* relrow = rel8 + ((size_t)b * SSc + iw + c) * SSc;
    const float ri = RI[(size_t)bh * SSc + iw + c];
    float* arow = att + ((size_t)bh * SSc + iw + c) * SSc;

    f32x4 Of[2] = {{0.f,0.f,0.f,0.f}, {0.f,0.f,0.f,0.f}};
    const int jbeg = z * (SSc / ZSP), jend = jbeg + SSc / ZSP;
    for (int j0 = jbeg; j0 < jend; j0 += 64) {
        __syncthreads();
        {
            const int j = tid >> 2, seg = tid & 3;
            *(short8*)&Kl[j * 40 + seg * 8] =
                *(const short8*)(Kbf + ((size_t)bh * SSc + j0 + j) * DKc + seg * 8);
            const short8 vv = *(const short8*)(Vbf + ((size_t)bh * SSc + j0 + j) * DKc + seg * 8);
            const int d0 = seg * 8;
#pragma unroll
            for (int k = 0; k < 8; ++k) Vt[(d0 + k) * 72 + j] = (u16)vv[k];
            if (tid < 64) msks8[tid] = (u8)(maskg[b * SSc + j0 + tid] == 0);
        }
        __syncthreads();

#pragma unroll
        for (int jg = 0; jg < 4; ++jg) {
            float4 prev;
            float* ap = &arow[j0 + jg * 16 + g * 4];
            if (addmode) prev = *(const float4*)ap;          // issue early, consumed late
            const short8 kf = *(const short8*)&Kl[(jg * 16 + c) * 40 + g * 8];
            f32x4 sc = __builtin_amdgcn_mfma_f32_16x16x32_bf16(kf, qf, (f32x4){0.f,0.f,0.f,0.f}, 0, 0, 0);
            const uchar4 rl4 = *(const uchar4*)&relrow[j0 + jg * 16 + g * 4];
            const uchar4 mk4 = *(const uchar4*)&msks8[jg * 16 + g * 4];
            const u8* rl = (const u8*)&rl4;
            const u8* mk = (const u8*)&mk4;
            float4 pv4;
            float* pp = (float*)&pv4;
#pragma unroll
            for (int r = 0; r < 4; ++r) {
                float sv = fmaf(sc[r], rks2[rl[r]], rbs2[rl[r]]);
                sv = mk[r] ? -1e30f : sv;
                pp[r] = exp2f(sv) * ri;
            }
            // P (bf16) [query][j] for PV
            ushort4 pb;
            pb.x = f2bf(pp[0]); pb.y = f2bf(pp[1]); pb.z = f2bf(pp[2]); pb.w = f2bf(pp[3]);
            *(ushort4*)&Pst[w][c * 72 + jg * 16 + g * 4] = pb;
            // f32 att RMW (vectorized)
            float4 o;
            if (addmode) {
                o.x = (prev.x + pv4.x) * scalef; o.y = (prev.y + pv4.y) * scalef;
                o.z = (prev.z + pv4.z) * scalef; o.w = (prev.w + pv4.w) * scalef;
            } else {
                o = (float4){pv4.x, pv4.y, pv4.z, pv4.w};
            }
            *(float4*)ap = o;
        }
        // PV: own-wave Pst only -> no block barrier needed (compiler inserts lgkmcnt)
#pragma unroll
        for (int jc = 0; jc < 2; ++jc) {
            const short8 pf = *(const short8*)&Pst[w][c * 72 + jc * 32 + g * 8];
#pragma unroll
            for (int dg = 0; dg < 2; ++dg) {
                const short8 vf = *(const short8*)&Vt[(dg * 16 + c) * 72 + jc * 32 + g * 8];
                Of[dg] = __builtin_amdgcn_mfma_f32_16x16x32_bf16(pf, vf, Of[dg], 0, 0, 0);
            }
        }
    }

#pragma unroll
    for (int dg = 0; dg < 2; ++dg) {
#pragma unroll
        for (int r = 0; r < 4; ++r) {
            OPart[(size_t)z * NRc * HDKc +
                  ((size_t)b * SSc + iw + g * 4 + r) * HDKc + h * DKc + dg * 16 + c] = Of[dg][r];
        }
    }
}

extern "C" void kernel_launch(void* const* d_in, const int* in_sizes, int n_in,
                              void* d_out, int out_size, void* d_ws, size_t ws_size,
                              hipStream_t stream)
{
    const size_t NF = (size_t)NRc * FFc;      // 1,048,576
    float* outx = (float*)d_out;
    float* att  = outx + NF;

    const size_t needed = (10 * NF + (ZSP + 1) * 32768) * sizeof(float);   // ~42.6 MB
    if (ws_size < needed) { fill_f32<<<dim3(4096), dim3(256), 0, stream>>>(outx, 1000.0f); return; }

    const float* x0   = (const float*)d_in[0];
    const int*   mask = (const int*)d_in[1];
    const int*   pos  = (const int*)d_in[2];
    const float* Wq   = (const float*)d_in[3];
    const float* bq   = (const float*)d_in[4];
    const float* Wk   = (const float*)d_in[5];
    const float* bk   = (const float*)d_in[6];
    const float* Wv   = (const float*)d_in[7];
    const float* bv   = (const float*)d_in[8];
    const float* Wo   = (const float*)d_in[9];
    const float* bo   = (const float*)d_in[10];
    const float* relk = (const float*)d_in[11];
    const float* relb = (const float*)d_in[12];
    const float* ln1g = (const float*)d_in[13];
    const float* ln1b = (const float*)d_in[14];
    const float* W1   = (const float*)d_in[15];
    const float* b1   = (const float*)d_in[16];
    const float* W2   = (const float*)d_in[17];
    const float* b2   = (const float*)d_in[18];
    const float* ln2g = (const float*)d_in[19];
    const float* ln2b = (const float*)d_in[20];

    float* ws = (float*)d_ws;
    float* slot0 = ws;            // X / MD(lo)
    float* slot1 = ws + 1 * NF;   // Qbf+Kbf / MD(hi)
    float* slot2 = ws + 2 * NF;   // Vbf / T1 / T2
    float* slot3 = ws + 3 * NF;   // HB
    u8*    rel8  = (u8*)(ws + 4 * NF);      // 2 NF f32 worth = 8.4 MB
    float* OPart = ws + 6 * NF;             // 4 x NF
    float* Lpart = ws + 10 * NF;            // ZSP x 32768
    float* RI    = ws + 10 * NF + ZSP * 32768;

    u16* Qbf = (u16*)slot1;
    u16* Kbf = Qbf + NF;
    u16* Vbf = (u16*)slot2;

    const dim3 blk(256);
    build_rel8<<<dim3(8192), blk, 0, stream>>>(pos, rel8);

    for (int l = 0; l < LLc; ++l) {
        const float* xin = l ? slot0 : x0;
        gemm_mfma<1, 1><<<dim3(4, 64), blk, 0, stream>>>(xin, 0,
            Wq + (size_t)l * FFc * HDKc, bq + l * HDKc, nullptr, Qbf, ISQD, HDKc, FFc);
        gemm_mfma<1, 1><<<dim3(4, 64), blk, 0, stream>>>(xin, 0,
            Wk + (size_t)l * FFc * HDKc, bk + l * HDKc, nullptr, Kbf, 1.0f, HDKc, FFc);
        gemm_mfma<1, 1><<<dim3(4, 64), blk, 0, stream>>>(xin, 0,
            Wv + (size_t)l * FFc * HDKc, bv + l * HDKc, nullptr, Vbf, 1.0f, HDKc, FFc);

        attn_stats<<<dim3(SSc / 64, BBc * HHc, ZSP), blk, 0, stream>>>(
            Qbf, Kbf, mask, rel8,
            relk + l * (2 * MMc + 1) * HHc, relb + l * (2 * MMc + 1) * HHc, Lpart);
        combine_l<<<dim3(BBc * HHc * SSc / 256), blk, 0, stream>>>(Lpart, RI);
        attn_probs<<<dim3(SSc / 64, BBc * HHc, ZSP), blk, 0, stream>>>(
            Qbf, Kbf, Vbf, mask, rel8,
            relk + l * (2 * MMc + 1) * HHc, relb + l * (2 * MMc + 1) * HHc, RI,
            att, OPart, l > 0 ? 1 : 0, l == LLc - 1 ? 0.25f : 1.0f);

        float* T1 = slot2;        // V dead
        gemm_mfma<0, ZSP><<<dim3(4, 64), blk, 0, stream>>>(OPart, NRc * HDKc,
            Wo + (size_t)l * HDKc * FFc, bo + l * FFc, T1, nullptr, 1.0f, FFc, HDKc);
        float* HB = slot3;
        ln_kernel<false><<<NRc / 4, blk, 0, stream>>>(T1, ln1g + l * FFc, ln1b + l * FFc, HB, (float*)nullptr);
        float* MD = slot0;        // X dead; MD spans slot0+slot1 chunked by rows
        float* T2 = slot2;
        for (int cch = 0; cch < 2; ++cch) {
            const float* hbC = HB + (size_t)cch * 2048 * FFc;
            float*       t2C = T2 + (size_t)cch * 2048 * FFc;
            gemm_mfma<2, 1><<<dim3(16, 32), blk, 0, stream>>>(hbC, 0,
                W1 + (size_t)l * FFc * F4c, b1 + l * F4c, MD, nullptr, 1.0f, F4c, FFc);
            gemm_mfma<0, 1><<<dim3(4, 32), blk, 0, stream>>>(MD, 0,
                W2 + (size_t)l * F4c * FFc, b2 + l * FFc, t2C, nullptr, 1.0f, FFc, F4c);
        }
        if (l == LLc - 1)
            ln_kernel<true><<<NRc / 4, blk, 0, stream>>>(T2, ln2g + l * FFc, ln2b + l * FFc, slot0, outx);
        else
            ln_kernel<false><<<NRc / 4, blk, 0, stream>>>(T2, ln2g + l * FFc, ln2b + l * FFc, slot0, (float*)nullptr);
    }
}